// Round 7
// baseline (110.699 us; speedup 1.0000x reference)
//
#include <hip/hip_runtime.h>
#include <math.h>

#define DD 1024
#define BB 16
#define GAMMA_C 0.1f

// ws layout (float offsets)
#define WS_COEFF 0        // 16*32 rbf coefficients
#define WS_YBAR  512      // [b][64] bin centroids
#define WS_CNT   1536     // [b][64] bin counts (float)
#define WS_MNMX  2560     // [b][2] row min/max
#define WS_C4    2592     // [tau][b][64]: logn - it*yb^2 - V4 (U5 denominator)
#define WS_C5    4640     // [tau][b][64]: logn - it*yb^2 - V5 (numerator)

__device__ __forceinline__ float wred_sum(float v){
  #pragma unroll
  for (int o = 32; o > 0; o >>= 1) v += __shfl_xor(v, o, 64);
  return v;
}
__device__ __forceinline__ float wred_max(float v){
  #pragma unroll
  for (int o = 32; o > 0; o >>= 1) v = fmaxf(v, __shfl_xor(v, o, 64));
  return v;
}
__device__ __forceinline__ float wred_min(float v){
  #pragma unroll
  for (int o = 32; o > 0; o >>= 1) v = fminf(v, __shfl_xor(v, o, 64));
  return v;
}

// softmax(beta) -> w_s[0..39] in LDS; contains __syncthreads()
__device__ __forceinline__ void block_softmax(const float* __restrict__ beta,
                                              float* w_s){
  int tid = threadIdx.x;
  if (tid < 64){
    float b = (tid < 40) ? beta[tid] : -3.0e38f;
    float m = wred_max(b);
    float e = (tid < 40) ? __expf(b - m) : 0.f;
    float s = wred_sum(e);
    if (tid < 40) w_s[tid] = e / s;
  }
  __syncthreads();
}

// lane owns 16 values at flat j = 4*(lane+64k)+c
__device__ __forceinline__ void load16(const float* __restrict__ p, int lane, float* r){
  const float4* p4 = (const float4*)p;
  #pragma unroll
  for (int k = 0; k < 4; k++){
    float4 a = p4[lane + 64*k];
    r[4*k+0] = a.x; r[4*k+1] = a.y; r[4*k+2] = a.z; r[4*k+3] = a.w;
  }
}

// =====================  kernel 1: prep  =====================================
// 256 threads/block, 200 blocks:
//  blocks [0,8):     sink units u=blk*4+wid, u -> (b=u>>1, tau=u&1).
//                    Wave-synchronous 64-bin hist + 5-iter Sinkhorn. No barriers.
//  blocks [8,136):   rbf: wave handles gw=(blk-8)*4+wid -> (b,p). Wave softmax.
//  blocks [136,200): elem ops (k0..31): writes out base = x + gamma*s.
__global__ __launch_bounds__(256) void prep_kernel(
    const float* __restrict__ x, const float* __restrict__ beta,
    const float* __restrict__ proto, float* __restrict__ out,
    float* __restrict__ ws){
  int blk = blockIdx.x, tid = threadIdx.x;
  int wid = tid >> 6, lane = tid & 63;

  if (blk < 8){
    // ---------------- wave-sync binned Sinkhorn ----------------
    __shared__ int   cnti[4][64];
    __shared__ float sumf[4][64];
    int u = blk*4 + wid;
    int b = u >> 1, tau = u & 1;
    float it = (tau == 0) ? 2.f : 1.f;
    float v[16];
    #pragma unroll
    for (int k = 0; k < 16; k++) v[k] = x[b*DD + lane + 64*k];
    float mx = v[0], mn = v[0];
    #pragma unroll
    for (int k = 1; k < 16; k++){ mx = fmaxf(mx, v[k]); mn = fminf(mn, v[k]); }
    mx = wred_max(mx); mn = wred_min(mn);
    cnti[wid][lane] = 0; sumf[wid][lane] = 0.f;
    float invw = 64.f / (mx - mn);
    #pragma unroll
    for (int k = 0; k < 16; k++){
      int g = min((int)((v[k] - mn) * invw), 63);
      atomicAdd(&cnti[wid][g], 1);
      atomicAdd(&sumf[wid][g], v[k]);
    }
    // same-wave LDS ops complete in program order; reads below see the atomics
    int n = cnti[wid][lane];
    float nf = (float)n;
    float yb  = n ? sumf[wid][lane] / nf : mn + (lane + 0.5f) / invw;
    float lnn = n ? __logf(nf) : -1e30f;
    float qg = it * yb * yb;
    float kg = 2.f * it * yb;
    float V = 0.f, C4 = 0.f, c;
    for (int iter = 0; iter < 5; iter++){
      c = lnn - qg - V;
      if (iter == 4) C4 = c;
      float s = 0.f;
      #pragma unroll
      for (int h = 0; h < 64; h++)
        s += __expf(fmaf(kg, __shfl(yb, h, 64), __shfl(c, h, 64)));
      float U = __logf(s) - qg;
      c = lnn - qg - U;
      s = 0.f;
      #pragma unroll
      for (int h = 0; h < 64; h++)
        s += __expf(fmaf(kg, __shfl(yb, h, 64), __shfl(c, h, 64)));
      V = __logf(s) - qg;
    }
    ws[WS_C4 + tau*1024 + b*64 + lane] = C4;
    ws[WS_C5 + tau*1024 + b*64 + lane] = lnn - qg - V;
    if (tau == 0){
      ws[WS_YBAR + b*64 + lane] = yb;
      ws[WS_CNT  + b*64 + lane] = nf;
      if (lane == 0){ ws[WS_MNMX + b*2] = mn; ws[WS_MNMX + b*2 + 1] = mx; }
    }

  } else if (blk < 136){
    // ---------------- rbf distances -> coeff (wave-sync) ----------------
    float bv = (lane < 40) ? beta[lane] : -3.0e38f;
    float m = wred_max(bv);
    float e = (lane < 40) ? __expf(bv - m) : 0.f;
    float ssum = wred_sum(e);
    float wl = e / ssum;
    float w32 = __shfl(wl, 32, 64), w33 = __shfl(wl, 33, 64), w34 = __shfl(wl, 34, 64);
    int gw = (blk - 8)*4 + wid;
    int b = gw >> 5, p = gw & 31;
    const float4* xr = (const float4*)(x + b*DD);
    const float4* pr = (const float4*)(proto + p*DD);
    float s = 0.f;
    #pragma unroll
    for (int k = 0; k < 4; k++){
      float4 a = xr[lane + 64*k], q = pr[lane + 64*k];
      float d0=a.x-q.x, d1=a.y-q.y, d2=a.z-q.z, d3=a.w-q.w;
      s += d0*d0 + d1*d1 + d2*d2 + d3*d3;
    }
    s = wred_sum(s);
    if (lane == 0){
      float cf = w32*__expf(-s*2.0f) + w33*__expf(-s*0.5f) + w34*__expf(-s*0.125f);
      ws[WS_COEFF + b*32 + p] = cf;
    }

  } else {
    // ---------------- elementwise + stencil ops ----------------
    __shared__ float w_s[40];
    block_softmax(beta, w_s);
    int idx = (blk - 136)*256 + tid;
    int b = idx >> 10, i = idx & 1023;
    const float* xr = x + b*DD;
    const float* w = w_s;
    float c = xr[i];
    float l = xr[i > 0 ? i-1 : 0];
    float r = xr[i < DD-1 ? i+1 : DD-1];
    float lap = l - 2.f*c + r;
    float s = 0.f;
    s += w[0]*__sinf(0.5f*c) + w[1]*__sinf(c) + w[2]*__sinf(2.f*c) + w[3]*__sinf(4.f*c);
    s += w[4]*__cosf(0.5f*c) + w[5]*__cosf(c) + w[6]*__cosf(2.f*c) + w[7]*__cosf(4.f*c);
    {
      float inner = 0.7978845608028654f * (c + 0.044715f*c*c*c);
      s += w[8] * 0.5f*c*(1.f + tanhf(inner));
      s += w[9] * tanhf(c);
      s += w[10] * (1.f / (1.f + __expf(-c)));
    }
    { float c2 = c*c; s += w[11]*c2 + w[12]*c2*c + w[13]*c2*c2; }
    {
      float ac = fabsf(c);
      s += w[14]*(c/(1.001f + 0.5f*ac)) + w[15]*(c/(1.001f + ac)) + w[16]*(c/(1.001f + 2.f*ac));
    }
    s += w[17]*(c + 0.001f*lap) + w[18]*(c + 0.003f*lap)
       + w[19]*(c + 0.01f*lap)  + w[20]*(c + 0.03f*lap);
    {
      float acc = w[21] * 0.786572f * c;
      {
        const float k1 = 0.106452f, k2 = 2.63876e-4f;
        float s1 = 0.f;
        s1 += k1 * ((i>=1 ? xr[i-1]:0.f) + (i<DD-1 ? xr[i+1]:0.f));
        s1 += k2 * ((i>=2 ? xr[i-2]:0.f) + (i<DD-2 ? xr[i+2]:0.f));
        acc += w[21] * s1;
      }
      {
        const float t1 = 0.242036f, t2 = 0.0540056f, t3 = 0.00443305f;
        float s1 = 0.399050f * c;
        s1 += t1 * ((i>=1 ? xr[i-1]:0.f) + (i<DD-1 ? xr[i+1]:0.f));
        s1 += t2 * ((i>=2 ? xr[i-2]:0.f) + (i<DD-2 ? xr[i+2]:0.f));
        s1 += t3 * ((i>=3 ? xr[i-3]:0.f) + (i<DD-3 ? xr[i+3]:0.f));
        acc += w[22] * s1;
      }
      {
        const float gk[7] = {0.199676f, 0.176216f, 0.121100f, 0.064825f,
                             0.027023f, 0.0087731f, 0.0022182f};
        float s1 = gk[0] * c;
        #pragma unroll
        for (int t = 1; t <= 6; t++)
          s1 += gk[t] * ((i>=t ? xr[i-t]:0.f) + (i<DD-t ? xr[i+t]:0.f));
        acc += w[23] * s1;
      }
      s += acc;
    }
    {
      const float taus[4] = {0.5f, 1.f, 2.f, 4.f};
      float m3 = fmaxf(l, fmaxf(c, r));
      #pragma unroll
      for (int ti = 0; ti < 4; ti++){
        float invt = 1.f / taus[ti];
        float e = __expf((l-m3)*invt) + __expf((c-m3)*invt) + __expf((r-m3)*invt);
        s += w[24 + ti] * (m3 + taus[ti]*__logf(e));
      }
    }
    {
      const float taus[4] = {0.5f, 1.f, 2.f, 4.f};
      float dl = fabsf(l - c), dr = fabsf(r - c);
      #pragma unroll
      for (int ti = 0; ti < 4; ti++){
        float invt = 1.f / taus[ti];
        float wl = __expf(-dl*invt), wr = __expf(-dr*invt);
        s += w[28 + ti] * ((wl*l + c + wr*r) / (wl + 1.f + wr));
      }
    }
    out[b*DD + i] = c + GAMMA_C * s;
  }
}

// =====================  kernel 2: fused B  ==================================
// 1024 blocks, block = output column i. 4 waves x 4 batches.
// Per (b,i): linear dot + rbf-proj + binned attention + binned sinkhorn apply.
__global__ __launch_bounds__(256) void fused_b(
    const float* __restrict__ x, const float* __restrict__ beta,
    const float* __restrict__ W, const float* __restrict__ bl,
    const float* __restrict__ proj,
    const float* __restrict__ wq, const float* __restrict__ wk,
    const float* __restrict__ wv, const float* __restrict__ wo,
    float* __restrict__ out, float* __restrict__ ws){
  __shared__ float w_s[40];
  block_softmax(beta, w_s);
  int i = blockIdx.x, tid = threadIdx.x;
  int wid = tid >> 6, lane = tid & 63;
  float tq = (lane < 8) ? wq[lane]*wk[lane] : 0.f;
  float tv = (lane < 8) ? wv[lane]*wo[lane] : 0.f;
  float qk = wred_sum(tq);
  float vo = wred_sum(tv);
  const float inv_sqrt8 = 0.35355339059327373f;

  float Wv[16];
  load16(W + (size_t)i*DD, lane, Wv);
  float projv = (lane < 32) ? proj[lane*DD + i] : 0.f;
  float w39 = w_s[39];
  float blv = bl[i];

  #pragma unroll
  for (int bq = 0; bq < 4; bq++){
    int b = wid*4 + bq;
    float xv[16];
    load16(x + b*DD, lane, xv);
    float p = 0.f;
    #pragma unroll
    for (int k = 0; k < 16; k++) p = fmaf(Wv[k], xv[k], p);
    float r = w39 * p;
    if (lane < 32) r = fmaf(ws[WS_COEFF + b*32 + lane], projv, r);

    float xi = x[b*DD + i];
    float ybg = ws[WS_YBAR + b*64 + lane];
    float ng  = ws[WS_CNT  + b*64 + lane];
    float c40 = ws[WS_C4 +        b*64 + lane];
    float c50 = ws[WS_C5 +        b*64 + lane];
    float c41 = ws[WS_C4 + 1024 + b*64 + lane];
    float c51 = ws[WS_C5 + 1024 + b*64 + lane];
    float k0 = 4.f*xi, k1 = 2.f*xi;
    float e40 = __expf(fmaf(k0, ybg, c40));
    float e50 = __expf(fmaf(k0, ybg, c50));
    float e41 = __expf(fmaf(k1, ybg, c41));
    float e51 = __expf(fmaf(k1, ybg, c51));
    float mn = ws[WS_MNMX + b*2], mx = ws[WS_MNMX + b*2 + 1];
    float a1 = qk * inv_sqrt8 * xi;
    float m1 = (a1 >= 0.f) ? a1*mx : a1*mn;
    float f  = __expf(fmaf(a1, ybg, -m1));
    float f2 = f*f;
    float s40 = wred_sum(e40);
    float s50 = wred_sum(e50*ybg);
    float s41 = wred_sum(e41);
    float s51 = wred_sum(e51*ybg);
    float s1  = wred_sum(ng*f);
    float sx1 = wred_sum(ng*f*ybg);
    float s2  = wred_sum(ng*f2);
    float sx2 = wred_sum(ng*f2*ybg);
    float rs  = wred_sum(r);
    if (lane == 0){
      float sink = w_s[37]*(s50/s40) + w_s[38]*(s51/s41);
      float attn = vo*(w_s[35]*(sx2/s2) + w_s[36]*(sx1/s1));
      atomicAdd(out + b*DD + i, GAMMA_C*(rs + w39*blv + sink + attn));
    }
  }
}

extern "C" void kernel_launch(void* const* d_in, const int* in_sizes, int n_in,
                              void* d_out, int out_size, void* d_ws, size_t ws_size,
                              hipStream_t stream){
  const float* x     = (const float*)d_in[0];
  const float* beta  = (const float*)d_in[1];
  const float* W     = (const float*)d_in[2];
  const float* bl    = (const float*)d_in[3];
  const float* wq    = (const float*)d_in[4];
  const float* wk    = (const float*)d_in[5];
  const float* wv    = (const float*)d_in[6];
  const float* wo    = (const float*)d_in[7];
  const float* proto = (const float*)d_in[8];
  const float* proj  = (const float*)d_in[9];
  float* out = (float*)d_out;
  float* ws  = (float*)d_ws;

  // wave-sync hist+Sinkhorn + rbf coeff + elem base
  prep_kernel<<<200, 256, 0, stream>>>(x, beta, proto, out, ws);
  // linear + proj + binned attention + binned sinkhorn apply
  fused_b<<<1024, 256, 0, stream>>>(x, beta, W, bl, proj, wq, wk, wv, wo, out, ws);
}